// Round 11
// baseline (1284.754 us; speedup 1.0000x reference)
//
#include <hip/hip_runtime.h>
#include <math.h>

#define G 5000
#define IN 64
#define D 128
#define E 240000
#define EG (E + G)
#define SLOPE 0.2f
#define GD (G * D)
#define MB 1024          // mlp1 blocks
#define GPB2 10
#define NBX (G / GPB2)   // 500 xlxr tiles
#define NB_PG 1250       // pergene blocks
#define NB_H 240         // hist blocks (61440 int4 units >= 61250)

__device__ __forceinline__ float leaky(float v) { return v >= 0.f ? v : SLOPE * v; }

// ---------------- K_A: pergene (blocks 0..1249) + hist (blocks 1250..1489) + zero out ----------------
__global__ __launch_bounds__(256) void k_fuseA(const float* __restrict__ x,
                                               const float* __restrict__ Win,
                                               const float* __restrict__ bin,
                                               float* __restrict__ h,
                                               const int* __restrict__ dstA,
                                               int* __restrict__ cnt,
                                               float* __restrict__ outz) {
    if (blockIdx.x == 0 && threadIdx.x == 0) *outz = 0.f;   // consumed only by k_final8 (stream-ordered)
    if (blockIdx.x < NB_PG) {
        // per-gene linear + relu (round-2 exact body)
        int g = (blockIdx.x * 256 + threadIdx.x) >> 6;
        int lane = threadIdx.x & 63;
        if (g >= G) return;
        float xv = x[g * IN + lane];
        const float* W = Win + (size_t)g * IN * D + lane * 2;
        float2 acc = *(const float2*)(bin + g * D + lane * 2);
#pragma unroll
        for (int i = 0; i < IN; ++i) {
            float xi = __shfl(xv, i);
            float2 w2 = *(const float2*)(W + (size_t)i * D);
            acc.x = fmaf(xi, w2.x, acc.x);
            acc.y = fmaf(xi, w2.y, acc.y);
        }
        float2 o = { fmaxf(acc.x, 0.f), fmaxf(acc.y, 0.f) };
        *(float2*)(h + g * D + lane * 2) = o;
    } else {
        // histogram (int4 reads) — independent, hides under pergene's HBM stream
        int unit = (blockIdx.x - NB_PG) * 256 + threadIdx.x;
        int base = unit * 4;
        if (base >= EG) return;
        if (base + 4 <= E) {
            int4 d4 = *(const int4*)(dstA + base);
            atomicAdd(&cnt[d4.x], 1);
            atomicAdd(&cnt[d4.y], 1);
            atomicAdd(&cnt[d4.z], 1);
            atomicAdd(&cnt[d4.w], 1);
        } else {
            for (int kk = 0; kk < 4; ++kk) {
                int i = base + kk;
                if (i < EG) {
                    int t = (i < E) ? dstA[i] : i - E;
                    atomicAdd(&cnt[t], 1);
                }
            }
        }
    }
}

// ---------------- K2: block 0 = scan; blocks 1..NBX = xlxr (round-8 exact) ----------------
__global__ __launch_bounds__(256) void k_xlxr_scan(const float* __restrict__ h,
                                                   const float* __restrict__ Wl,
                                                   const float* __restrict__ bl,
                                                   const float* __restrict__ Wr,
                                                   const float* __restrict__ br,
                                                   float* __restrict__ xl,
                                                   float* __restrict__ xr,
                                                   const int* __restrict__ cnt,
                                                   int* __restrict__ rowptr,
                                                   int* __restrict__ cursor) {
    if (blockIdx.x == 0) {
        __shared__ int ssum[256];
        int tid = threadIdx.x;
        const int CH = (G + 255) / 256;   // 20
        int base = tid * CH;
        int s = 0;
        for (int k = 0; k < CH; ++k) { int idx = base + k; if (idx < G) s += cnt[idx]; }
        ssum[tid] = s;
        __syncthreads();
        for (int off = 1; off < 256; off <<= 1) {
            int v = ssum[tid];
            int add = (tid >= off) ? ssum[tid - off] : 0;
            __syncthreads();
            ssum[tid] = v + add;
            __syncthreads();
        }
        int run = (tid == 0) ? 0 : ssum[tid - 1];
        for (int k = 0; k < CH; ++k) {
            int idx = base + k;
            if (idx < G) { rowptr[idx] = run; cursor[idx] = run; run += cnt[idx]; }
        }
        if (tid == 255) rowptr[G] = run;   // == EG
        return;
    }
    int g0 = (blockIdx.x - 1) * GPB2;
    int wv = __builtin_amdgcn_readfirstlane(threadIdx.x >> 6);  // wave id 0..3, SGPR
    int half = wv >> 1;            // 0: xl/Wl, 1: xr/Wr
    int sub  = wv & 1;             // gene subset
    int lane = threadIdx.x & 63;
    int d = lane * 2;
    const float* W = half ? Wr : Wl;
    const float* bb = half ? br : bl;
    float* o = half ? xr : xl;
    float2 bv = *(const float2*)(bb + d);
    float2 acc0 = bv, acc1 = bv, acc2 = bv, acc3 = bv, acc4 = bv;
    const float* hr = h + (size_t)(g0 + sub * 5) * D;   // 5 consecutive gene rows
    for (int k4 = 0; k4 < 32; ++k4) {
        int k = k4 * 4;
        float2 w0 = *(const float2*)(W + (k + 0) * D + d);
        float2 w1 = *(const float2*)(W + (k + 1) * D + d);
        float2 w2 = *(const float2*)(W + (k + 2) * D + d);
        float2 w3 = *(const float2*)(W + (k + 3) * D + d);
        float4 h0 = *(const float4*)(hr + 0 * D + k);
        float4 h1 = *(const float4*)(hr + 1 * D + k);
        float4 h2 = *(const float4*)(hr + 2 * D + k);
        float4 h3 = *(const float4*)(hr + 3 * D + k);
        float4 h4 = *(const float4*)(hr + 4 * D + k);
        acc0.x = fmaf(h0.x, w0.x, acc0.x); acc0.y = fmaf(h0.x, w0.y, acc0.y);
        acc0.x = fmaf(h0.y, w1.x, acc0.x); acc0.y = fmaf(h0.y, w1.y, acc0.y);
        acc0.x = fmaf(h0.z, w2.x, acc0.x); acc0.y = fmaf(h0.z, w2.y, acc0.y);
        acc0.x = fmaf(h0.w, w3.x, acc0.x); acc0.y = fmaf(h0.w, w3.y, acc0.y);
        acc1.x = fmaf(h1.x, w0.x, acc1.x); acc1.y = fmaf(h1.x, w0.y, acc1.y);
        acc1.x = fmaf(h1.y, w1.x, acc1.x); acc1.y = fmaf(h1.y, w1.y, acc1.y);
        acc1.x = fmaf(h1.z, w2.x, acc1.x); acc1.y = fmaf(h1.z, w2.y, acc1.y);
        acc1.x = fmaf(h1.w, w3.x, acc1.x); acc1.y = fmaf(h1.w, w3.y, acc1.y);
        acc2.x = fmaf(h2.x, w0.x, acc2.x); acc2.y = fmaf(h2.x, w0.y, acc2.y);
        acc2.x = fmaf(h2.y, w1.x, acc2.x); acc2.y = fmaf(h2.y, w1.y, acc2.y);
        acc2.x = fmaf(h2.z, w2.x, acc2.x); acc2.y = fmaf(h2.z, w2.y, acc2.y);
        acc2.x = fmaf(h2.w, w3.x, acc2.x); acc2.y = fmaf(h2.w, w3.y, acc2.y);
        acc3.x = fmaf(h3.x, w0.x, acc3.x); acc3.y = fmaf(h3.x, w0.y, acc3.y);
        acc3.x = fmaf(h3.y, w1.x, acc3.x); acc3.y = fmaf(h3.y, w1.y, acc3.y);
        acc3.x = fmaf(h3.z, w2.x, acc3.x); acc3.y = fmaf(h3.z, w2.y, acc3.y);
        acc3.x = fmaf(h3.w, w3.x, acc3.x); acc3.y = fmaf(h3.w, w3.y, acc3.y);
        acc4.x = fmaf(h4.x, w0.x, acc4.x); acc4.y = fmaf(h4.x, w0.y, acc4.y);
        acc4.x = fmaf(h4.y, w1.x, acc4.x); acc4.y = fmaf(h4.y, w1.y, acc4.y);
        acc4.x = fmaf(h4.z, w2.x, acc4.x); acc4.y = fmaf(h4.z, w2.y, acc4.y);
        acc4.x = fmaf(h4.w, w3.x, acc4.x); acc4.y = fmaf(h4.w, w3.y, acc4.y);
    }
    int gbase = g0 + sub * 5;
    *(float2*)(o + (size_t)(gbase + 0) * D + d) = acc0;
    *(float2*)(o + (size_t)(gbase + 1) * D + d) = acc1;
    *(float2*)(o + (size_t)(gbase + 2) * D + d) = acc2;
    *(float2*)(o + (size_t)(gbase + 3) * D + d) = acc3;
    *(float2*)(o + (size_t)(gbase + 4) * D + d) = acc4;
}

// ---------------- K3: bucket edges by destination (round-8 exact) ----------------
__global__ __launch_bounds__(256) void k_bucket(const int* __restrict__ srcA,
                                                const int* __restrict__ dstA,
                                                int* __restrict__ cursor,
                                                int* __restrict__ ssrc) {
    int base = (blockIdx.x * 256 + threadIdx.x) * 4;
    if (base >= EG) return;
    if (base + 4 <= E) {
        int4 s4 = *(const int4*)(srcA + base);
        int4 d4 = *(const int4*)(dstA + base);
        int p;
        p = atomicAdd(&cursor[d4.x], 1); ssrc[p] = s4.x;
        p = atomicAdd(&cursor[d4.y], 1); ssrc[p] = s4.y;
        p = atomicAdd(&cursor[d4.z], 1); ssrc[p] = s4.z;
        p = atomicAdd(&cursor[d4.w], 1); ssrc[p] = s4.w;
    } else {
        for (int kk = 0; kk < 4; ++kk) {
            int i = base + kk;
            if (i < EG) {
                int s, t;
                if (i < E) { s = srcA[i]; t = dstA[i]; }
                else { s = i - E; t = s; }
                int p = atomicAdd(&cursor[t], 1);
                ssrc[p] = s;
            }
        }
    }
}

// rep variant: same work, throwaway destinations (cursor2 garbage-init is fine; writes masked into ssrc2 window)
__global__ __launch_bounds__(256) void k_bucket_rep(const int* __restrict__ srcA,
                                                    const int* __restrict__ dstA,
                                                    unsigned int* __restrict__ cursor2,
                                                    int* __restrict__ ssrc2) {
    int base0 = (blockIdx.x * 256 + threadIdx.x) * 4;
    if (base0 >= EG) return;
    for (int rep = 0; rep < 48; ++rep) {
        int base = base0;
        if (base + 4 <= E) {
            int4 s4 = *(const int4*)(srcA + base);
            int4 d4 = *(const int4*)(dstA + base);
            unsigned p;
            p = atomicAdd(&cursor2[d4.x], 1u); ssrc2[p & 0xFFFFFu] = s4.x;
            p = atomicAdd(&cursor2[d4.y], 1u); ssrc2[p & 0xFFFFFu] = s4.y;
            p = atomicAdd(&cursor2[d4.z], 1u); ssrc2[p & 0xFFFFFu] = s4.z;
            p = atomicAdd(&cursor2[d4.w], 1u); ssrc2[p & 0xFFFFFu] = s4.w;
        } else {
            for (int kk = 0; kk < 4; ++kk) {
                int i = base + kk;
                if (i < EG) {
                    int s, t;
                    if (i < E) { s = srcA[i]; t = dstA[i]; }
                    else { s = i - E; t = s; }
                    unsigned p = atomicAdd(&cursor2[t], 1u);
                    ssrc2[p & 0xFFFFFu] = s;
                }
            }
        }
    }
}

// ---------------- K4: GAT aggregation (round-8 exact body, shared) ----------------
__device__ __forceinline__ void agg_body(int t, int lane,
                                         const int* __restrict__ rowptr,
                                         const int* __restrict__ ssrc,
                                         const float* __restrict__ xl,
                                         const float* __restrict__ xr,
                                         float2 a, float2 b2,
                                         float* __restrict__ f) {
    float2 r2 = *(const float2*)(xr + t * D + lane * 2);
    float2 acc = { 0.f, 0.f };
    float z = 0.f;
    int e0 = rowptr[t], e1 = rowptr[t + 1];
    for (int base = e0; base < e1; base += 64) {
        int nv = e1 - base; if (nv > 64) nv = 64;
        int sv = ssrc[base + (lane < nv ? lane : nv - 1)];   // coalesced preload
        int e = 0;
        for (; e + 4 <= nv; e += 4) {
            int s0 = __shfl(sv, e), s1 = __shfl(sv, e + 1);
            int s2 = __shfl(sv, e + 2), s3 = __shfl(sv, e + 3);
            float2 l0 = *(const float2*)(xl + s0 * D + lane * 2);
            float2 l1 = *(const float2*)(xl + s1 * D + lane * 2);
            float2 l2 = *(const float2*)(xl + s2 * D + lane * 2);
            float2 l3 = *(const float2*)(xl + s3 * D + lane * 2);
            float v0 = leaky(l0.x + r2.x) * a.x + leaky(l0.y + r2.y) * a.y;
            float v1 = leaky(l1.x + r2.x) * a.x + leaky(l1.y + r2.y) * a.y;
            float v2 = leaky(l2.x + r2.x) * a.x + leaky(l2.y + r2.y) * a.y;
            float v3 = leaky(l3.x + r2.x) * a.x + leaky(l3.y + r2.y) * a.y;
#pragma unroll
            for (int off = 32; off; off >>= 1) {
                v0 += __shfl_xor(v0, off);
                v1 += __shfl_xor(v1, off);
                v2 += __shfl_xor(v2, off);
                v3 += __shfl_xor(v3, off);
            }
            float w0 = expf(v0), w1 = expf(v1), w2 = expf(v2), w3 = expf(v3);
            z += (w0 + w1) + (w2 + w3);
            acc.x = fmaf(w0, l0.x, acc.x); acc.y = fmaf(w0, l0.y, acc.y);
            acc.x = fmaf(w1, l1.x, acc.x); acc.y = fmaf(w1, l1.y, acc.y);
            acc.x = fmaf(w2, l2.x, acc.x); acc.y = fmaf(w2, l2.y, acc.y);
            acc.x = fmaf(w3, l3.x, acc.x); acc.y = fmaf(w3, l3.y, acc.y);
        }
        for (; e < nv; ++e) {
            int s = __shfl(sv, e);
            float2 l = *(const float2*)(xl + s * D + lane * 2);
            float v = leaky(l.x + r2.x) * a.x + leaky(l.y + r2.y) * a.y;
#pragma unroll
            for (int off = 32; off; off >>= 1) v += __shfl_xor(v, off);
            float w = expf(v);
            z += w;
            acc.x = fmaf(w, l.x, acc.x);
            acc.y = fmaf(w, l.y, acc.y);
        }
    }
    float inv = 1.f / z;
    float2 o = { leaky(acc.x * inv + b2.x), leaky(acc.y * inv + b2.y) };
    *(float2*)(f + t * D + lane * 2) = o;
}

__global__ __launch_bounds__(256) void k_agg(const int* __restrict__ rowptr,
                                             const int* __restrict__ ssrc,
                                             const float* __restrict__ xl,
                                             const float* __restrict__ xr,
                                             const float* __restrict__ att,
                                             const float* __restrict__ bias,
                                             float* __restrict__ f) {
    int t = (blockIdx.x * 256 + threadIdx.x) >> 6;
    int lane = threadIdx.x & 63;
    if (t >= G) return;
    float2 a  = *(const float2*)(att + lane * 2);
    float2 b2 = *(const float2*)(bias + lane * 2);
    agg_body(t, lane, rowptr, ssrc, xl, xr, a, b2, f);
}

// rep variant: exact same work 16x (f rewritten with identical values — idempotent)
__global__ __launch_bounds__(256) void k_agg_rep(const int* __restrict__ rowptr,
                                                 const int* __restrict__ ssrc,
                                                 const float* __restrict__ xl,
                                                 const float* __restrict__ xr,
                                                 const float* __restrict__ att,
                                                 const float* __restrict__ bias,
                                                 float* __restrict__ f) {
    int t = (blockIdx.x * 256 + threadIdx.x) >> 6;
    int lane = threadIdx.x & 63;
    if (t >= G) return;
    float2 a  = *(const float2*)(att + lane * 2);
    float2 b2 = *(const float2*)(bias + lane * 2);
    for (int rep = 0; rep < 16; ++rep)
        agg_body(t, lane, rowptr, ssrc, xl, xr, a, b2, f);
}

// ---------------- K5: MLP layer 1 (round-2 exact) ----------------
__global__ __launch_bounds__(256) void k_mlp1(const float* __restrict__ f,
                                              const float* __restrict__ W1,
                                              float* __restrict__ partials) {
    const int rpb = GD / MB;              // 625 rows per block
    int r0 = blockIdx.x * rpb;
    int wave = threadIdx.x >> 6, lane = threadIdx.x & 63;
    float2 acc = { 0.f, 0.f };
#pragma unroll 4
    for (int n = r0 + wave; n < r0 + rpb; n += 4) {
        float fv = f[n];
        float2 w2 = *(const float2*)(W1 + (size_t)n * D + lane * 2);
        acc.x = fmaf(fv, w2.x, acc.x);
        acc.y = fmaf(fv, w2.y, acc.y);
    }
    __shared__ float2 red[4][64];
    red[wave][lane] = acc;
    __syncthreads();
    if (wave == 0) {
        float2 s = red[0][lane];
        s.x += red[1][lane].x + red[2][lane].x + red[3][lane].x;
        s.y += red[1][lane].y + red[2][lane].y + red[3][lane].y;
        *(float2*)(partials + blockIdx.x * D + lane * 2) = s;
    }
}

// ---------------- K6: 8-block column-sliced reduce + relu + dot W2 (round-10 exact) ----------------
__global__ __launch_bounds__(1024) void k_final8(const float* __restrict__ partials,
                                                 const float* __restrict__ b1,
                                                 const float* __restrict__ W2,
                                                 const float* __restrict__ b2,
                                                 float* __restrict__ out) {
    int tid = threadIdx.x;
    int rg = tid >> 4;            // row group 0..63
    int cl = tid & 15;            // local column
    int c = blockIdx.x * 16 + cl; // global column
    float s = 0.f;
    for (int r = rg; r < MB; r += 64) s += partials[r * D + c];
    __shared__ float red[64][16];
    red[rg][cl] = s;
    __syncthreads();
    if (tid < 128) {
        int cc = tid & 15, seg = tid >> 4;    // seg 0..7
        float t2 = red[seg * 8][cc];
        for (int m = 1; m < 8; ++m) t2 += red[seg * 8 + m][cc];
        red[seg * 8][cc] = t2;
    }
    __syncthreads();
    if (tid < 16) {
        float tot = 0.f;
        for (int m = 0; m < 8; ++m) tot += red[m * 8][tid];
        float h1 = fmaxf(tot + b1[blockIdx.x * 16 + tid], 0.f);
        red[0][tid] = h1 * W2[blockIdx.x * 16 + tid];
    }
    __syncthreads();
    if (tid == 0) {
        float o = 0.f;
        for (int m = 0; m < 16; ++m) o += red[0][m];
        if (blockIdx.x == 0) o += b2[0];
        atomicAdd(out, o);
    }
}

extern "C" void kernel_launch(void* const* d_in, const int* in_sizes, int n_in,
                              void* d_out, int out_size, void* d_ws, size_t ws_size,
                              hipStream_t stream) {
    const float* x    = (const float*)d_in[0];
    const int*   ei   = (const int*)d_in[1];
    const float* Win  = (const float*)d_in[2];
    const float* bin  = (const float*)d_in[3];
    const float* Wl   = (const float*)d_in[4];
    const float* bl   = (const float*)d_in[5];
    const float* Wr   = (const float*)d_in[6];
    const float* br   = (const float*)d_in[7];
    const float* att  = (const float*)d_in[8];
    const float* bias = (const float*)d_in[9];
    const float* W1   = (const float*)d_in[10];
    const float* b1   = (const float*)d_in[11];
    const float* W2   = (const float*)d_in[12];
    const float* b2   = (const float*)d_in[13];
    float* out = (float*)d_out;

    float* ws       = (float*)d_ws;
    float* h        = ws;                 // GD
    float* xl       = h  + GD;            // GD
    float* xr       = xl + GD;            // GD
    float* f        = xr + GD;            // GD
    float* partials = f  + GD;            // MB*D
    int*   ssrc     = (int*)(partials + (size_t)MB * D);  // EG
    int*   cnt      = ssrc + EG;          // G
    int*   rowptr   = cnt + G;            // G+1
    int*   cursor   = rowptr + G + 1;     // G
    // throwaway buffers for rep-kernels (never read for output)
    unsigned int* cursor2 = (unsigned int*)(cursor + G);  // G
    int*   ssrc2   = (int*)(cursor2 + G);                 // 1<<20

    const int* srcA = ei;
    const int* dstA = ei + E;

    hipMemsetAsync(cnt, 0, G * sizeof(int), stream);
    k_fuseA<<<NB_PG + NB_H, 256, 0, stream>>>(x, Win, bin, h, dstA, cnt, out);
    k_xlxr_scan<<<NBX + 1, 256, 0, stream>>>(h, Wl, bl, Wr, br, xl, xr, cnt, rowptr, cursor);
    k_bucket<<<(EG / 4 + 255) / 256, 256, 0, stream>>>(srcA, dstA, cursor, ssrc);
    k_agg<<<(G * 64) / 256, 256, 0, stream>>>(rowptr, ssrc, xl, xr, att, bias, f);
    k_mlp1<<<MB, 256, 0, stream>>>(f, W1, partials);
    k_final8<<<8, 1024, 0, stream>>>(partials, b1, W2, b2, out);

    // ---- ATTRIBUTION reps (after output is final; idempotent / throwaway) ----
    k_agg_rep<<<(G * 64) / 256, 256, 0, stream>>>(rowptr, ssrc, xl, xr, att, bias, f);
    k_bucket_rep<<<(EG / 4 + 255) / 256, 256, 0, stream>>>(srcA, dstA, cursor2, ssrc2);
}

// Round 12
// 178.237 us; speedup vs baseline: 7.2081x; 7.2081x over previous
//
#include <hip/hip_runtime.h>
#include <math.h>

#define G 5000
#define IN 64
#define D 128
#define E 240000
#define EG (E + G)
#define SLOPE 0.2f
#define GD (G * D)
#define MB 1024          // mlp1 blocks
#define GPB2 10
#define NBX (G / GPB2)   // 500 xlxr tiles
#define NB_PG 1250       // pergene blocks
#define NB_H 240         // hist/bucket blocks (61440 int4 units >= 61250)

__device__ __forceinline__ float leaky(float v) { return v >= 0.f ? v : SLOPE * v; }

// ---------------- K_A: pergene (blocks 0..1249) + hist (blocks 1250..1489) + zero out ----------------
__global__ __launch_bounds__(256) void k_fuseA(const float* __restrict__ x,
                                               const float* __restrict__ Win,
                                               const float* __restrict__ bin,
                                               float* __restrict__ h,
                                               const int* __restrict__ dstA,
                                               int* __restrict__ cnt,
                                               float* __restrict__ outz) {
    if (blockIdx.x == 0 && threadIdx.x == 0) *outz = 0.f;   // consumed only by k_final8 (stream-ordered)
    if (blockIdx.x < NB_PG) {
        int g = (blockIdx.x * 256 + threadIdx.x) >> 6;
        int lane = threadIdx.x & 63;
        if (g >= G) return;
        float xv = x[g * IN + lane];
        const float* W = Win + (size_t)g * IN * D + lane * 2;
        float2 acc = *(const float2*)(bin + g * D + lane * 2);
#pragma unroll
        for (int i = 0; i < IN; ++i) {
            float xi = __shfl(xv, i);
            float2 w2 = *(const float2*)(W + (size_t)i * D);
            acc.x = fmaf(xi, w2.x, acc.x);
            acc.y = fmaf(xi, w2.y, acc.y);
        }
        float2 o = { fmaxf(acc.x, 0.f), fmaxf(acc.y, 0.f) };
        *(float2*)(h + g * D + lane * 2) = o;
    } else {
        int unit = (blockIdx.x - NB_PG) * 256 + threadIdx.x;
        int base = unit * 4;
        if (base >= EG) return;
        if (base + 4 <= E) {
            int4 d4 = *(const int4*)(dstA + base);
            atomicAdd(&cnt[d4.x], 1);
            atomicAdd(&cnt[d4.y], 1);
            atomicAdd(&cnt[d4.z], 1);
            atomicAdd(&cnt[d4.w], 1);
        } else {
            for (int kk = 0; kk < 4; ++kk) {
                int i = base + kk;
                if (i < EG) {
                    int t = (i < E) ? dstA[i] : i - E;
                    atomicAdd(&cnt[t], 1);
                }
            }
        }
    }
}

// ---------------- K_scan: exclusive scan (single block, round-8 exact body) ----------------
__global__ __launch_bounds__(256) void k_scan(const int* __restrict__ cnt,
                                              int* __restrict__ rowptr,
                                              int* __restrict__ cursor) {
    __shared__ int ssum[256];
    int tid = threadIdx.x;
    const int CH = (G + 255) / 256;   // 20
    int base = tid * CH;
    int s = 0;
    for (int k = 0; k < CH; ++k) { int idx = base + k; if (idx < G) s += cnt[idx]; }
    ssum[tid] = s;
    __syncthreads();
    for (int off = 1; off < 256; off <<= 1) {
        int v = ssum[tid];
        int add = (tid >= off) ? ssum[tid - off] : 0;
        __syncthreads();
        ssum[tid] = v + add;
        __syncthreads();
    }
    int run = (tid == 0) ? 0 : ssum[tid - 1];
    for (int k = 0; k < CH; ++k) {
        int idx = base + k;
        if (idx < G) { rowptr[idx] = run; cursor[idx] = run; run += cnt[idx]; }
    }
    if (tid == 255) rowptr[G] = run;   // == EG
}

// ---------------- K_fuse2: xlxr (blocks 0..NBX-1) + bucket (blocks NBX..NBX+NB_H-1) ----------------
__global__ __launch_bounds__(256) void k_fuse2(const float* __restrict__ h,
                                               const float* __restrict__ Wl,
                                               const float* __restrict__ bl,
                                               const float* __restrict__ Wr,
                                               const float* __restrict__ br,
                                               float* __restrict__ xl,
                                               float* __restrict__ xr,
                                               const int* __restrict__ srcA,
                                               const int* __restrict__ dstA,
                                               int* __restrict__ cursor,
                                               int* __restrict__ ssrc) {
    if (blockIdx.x < NBX) {
        // xlxr (round-8 exact body)
        int g0 = blockIdx.x * GPB2;
        int wv = __builtin_amdgcn_readfirstlane(threadIdx.x >> 6);
        int half = wv >> 1;
        int sub  = wv & 1;
        int lane = threadIdx.x & 63;
        int d = lane * 2;
        const float* W = half ? Wr : Wl;
        const float* bb = half ? br : bl;
        float* o = half ? xr : xl;
        float2 bv = *(const float2*)(bb + d);
        float2 acc0 = bv, acc1 = bv, acc2 = bv, acc3 = bv, acc4 = bv;
        const float* hr = h + (size_t)(g0 + sub * 5) * D;
        for (int k4 = 0; k4 < 32; ++k4) {
            int k = k4 * 4;
            float2 w0 = *(const float2*)(W + (k + 0) * D + d);
            float2 w1 = *(const float2*)(W + (k + 1) * D + d);
            float2 w2 = *(const float2*)(W + (k + 2) * D + d);
            float2 w3 = *(const float2*)(W + (k + 3) * D + d);
            float4 h0 = *(const float4*)(hr + 0 * D + k);
            float4 h1 = *(const float4*)(hr + 1 * D + k);
            float4 h2 = *(const float4*)(hr + 2 * D + k);
            float4 h3 = *(const float4*)(hr + 3 * D + k);
            float4 h4 = *(const float4*)(hr + 4 * D + k);
            acc0.x = fmaf(h0.x, w0.x, acc0.x); acc0.y = fmaf(h0.x, w0.y, acc0.y);
            acc0.x = fmaf(h0.y, w1.x, acc0.x); acc0.y = fmaf(h0.y, w1.y, acc0.y);
            acc0.x = fmaf(h0.z, w2.x, acc0.x); acc0.y = fmaf(h0.z, w2.y, acc0.y);
            acc0.x = fmaf(h0.w, w3.x, acc0.x); acc0.y = fmaf(h0.w, w3.y, acc0.y);
            acc1.x = fmaf(h1.x, w0.x, acc1.x); acc1.y = fmaf(h1.x, w0.y, acc1.y);
            acc1.x = fmaf(h1.y, w1.x, acc1.x); acc1.y = fmaf(h1.y, w1.y, acc1.y);
            acc1.x = fmaf(h1.z, w2.x, acc1.x); acc1.y = fmaf(h1.z, w2.y, acc1.y);
            acc1.x = fmaf(h1.w, w3.x, acc1.x); acc1.y = fmaf(h1.w, w3.y, acc1.y);
            acc2.x = fmaf(h2.x, w0.x, acc2.x); acc2.y = fmaf(h2.x, w0.y, acc2.y);
            acc2.x = fmaf(h2.y, w1.x, acc2.x); acc2.y = fmaf(h2.y, w1.y, acc2.y);
            acc2.x = fmaf(h2.z, w2.x, acc2.x); acc2.y = fmaf(h2.z, w2.y, acc2.y);
            acc2.x = fmaf(h2.w, w3.x, acc2.x); acc2.y = fmaf(h2.w, w3.y, acc2.y);
            acc3.x = fmaf(h3.x, w0.x, acc3.x); acc3.y = fmaf(h3.x, w0.y, acc3.y);
            acc3.x = fmaf(h3.y, w1.x, acc3.x); acc3.y = fmaf(h3.y, w1.y, acc3.y);
            acc3.x = fmaf(h3.z, w2.x, acc3.x); acc3.y = fmaf(h3.z, w2.y, acc3.y);
            acc3.x = fmaf(h3.w, w3.x, acc3.x); acc3.y = fmaf(h3.w, w3.y, acc3.y);
            acc4.x = fmaf(h4.x, w0.x, acc4.x); acc4.y = fmaf(h4.x, w0.y, acc4.y);
            acc4.x = fmaf(h4.y, w1.x, acc4.x); acc4.y = fmaf(h4.y, w1.y, acc4.y);
            acc4.x = fmaf(h4.z, w2.x, acc4.x); acc4.y = fmaf(h4.z, w2.y, acc4.y);
            acc4.x = fmaf(h4.w, w3.x, acc4.x); acc4.y = fmaf(h4.w, w3.y, acc4.y);
        }
        int gbase = g0 + sub * 5;
        *(float2*)(o + (size_t)(gbase + 0) * D + d) = acc0;
        *(float2*)(o + (size_t)(gbase + 1) * D + d) = acc1;
        *(float2*)(o + (size_t)(gbase + 2) * D + d) = acc2;
        *(float2*)(o + (size_t)(gbase + 3) * D + d) = acc3;
        *(float2*)(o + (size_t)(gbase + 4) * D + d) = acc4;
    } else {
        // bucket (round-8 exact body) — overlaps with xlxr blocks
        int base = ((blockIdx.x - NBX) * 256 + threadIdx.x) * 4;
        if (base >= EG) return;
        if (base + 4 <= E) {
            int4 s4 = *(const int4*)(srcA + base);
            int4 d4 = *(const int4*)(dstA + base);
            int p;
            p = atomicAdd(&cursor[d4.x], 1); ssrc[p] = s4.x;
            p = atomicAdd(&cursor[d4.y], 1); ssrc[p] = s4.y;
            p = atomicAdd(&cursor[d4.z], 1); ssrc[p] = s4.z;
            p = atomicAdd(&cursor[d4.w], 1); ssrc[p] = s4.w;
        } else {
            for (int kk = 0; kk < 4; ++kk) {
                int i = base + kk;
                if (i < EG) {
                    int s, t;
                    if (i < E) { s = srcA[i]; t = dstA[i]; }
                    else { s = i - E; t = s; }
                    int p = atomicAdd(&cursor[t], 1);
                    ssrc[p] = s;
                }
            }
        }
    }
}

// ---------------- K4: GAT aggregation — lane-per-edge logits, LDS w/s, col-major aggregate ----------------
__global__ __launch_bounds__(256) void k_agg(const int* __restrict__ rowptr,
                                             const int* __restrict__ ssrc,
                                             const float* __restrict__ xl,
                                             const float* __restrict__ xr,
                                             const float* __restrict__ att,
                                             const float* __restrict__ bias,
                                             float* __restrict__ f) {
    int wid = threadIdx.x >> 6;
    int lane = threadIdx.x & 63;
    int t = __builtin_amdgcn_readfirstlane(blockIdx.x * 4 + wid);   // wave-uniform -> scalar loads
    if (t >= G) return;
    __shared__ float w_lds[4][64];
    __shared__ int   s_lds[4][64];
    const float* xrt = xr + (size_t)t * D;       // uniform pointer
    int lane2 = lane * 2;
    float2 acc = { 0.f, 0.f };
    float z = 0.f;
    int e0 = rowptr[t], e1 = rowptr[t + 1];
    for (int base = e0; base < e1; base += 64) {
        int nv = e1 - base; if (nv > 64) nv = 64;
        int myე = base + lane;
        int s = ssrc[myე < e1 ? myე : e1 - 1];   // coalesced per-lane edge src
        // ---- phase 1: per-lane full-D logit (no cross-lane ops) ----
        const float* xls = xl + (size_t)s * D;
        float v0 = 0.f, v1 = 0.f;
#pragma unroll
        for (int dc = 0; dc < D; dc += 8) {
            float4 xa = *(const float4*)(xls + dc);
            float4 xb = *(const float4*)(xls + dc + 4);
            float4 ra = *(const float4*)(xrt + dc);      // uniform -> s_load
            float4 rb = *(const float4*)(xrt + dc + 4);
            float4 aa = *(const float4*)(att + dc);      // uniform -> s_load
            float4 ab = *(const float4*)(att + dc + 4);
            v0 = fmaf(aa.x, leaky(xa.x + ra.x), v0);
            v0 = fmaf(aa.y, leaky(xa.y + ra.y), v0);
            v0 = fmaf(aa.z, leaky(xa.z + ra.z), v0);
            v0 = fmaf(aa.w, leaky(xa.w + ra.w), v0);
            v1 = fmaf(ab.x, leaky(xb.x + rb.x), v1);
            v1 = fmaf(ab.y, leaky(xb.y + rb.y), v1);
            v1 = fmaf(ab.z, leaky(xb.z + rb.z), v1);
            v1 = fmaf(ab.w, leaky(xb.w + rb.w), v1);
        }
        float w = (lane < nv) ? expf(v0 + v1) : 0.f;
        z += w;
        w_lds[wid][lane] = w;     // same-wave write->read: no barrier needed (lockstep)
        s_lds[wid][lane] = s;
        // ---- phase 2: column-major weighted aggregate (uniform LDS broadcast reads) ----
        for (int e = 0; e < nv; e += 4) {
            float4 w4 = *(const float4*)&w_lds[wid][e];   // uniform addr: broadcast
            int4   s4 = *(const int4*)&s_lds[wid][e];
            float2 l0 = *(const float2*)(xl + (size_t)s4.x * D + lane2);
            float2 l1 = *(const float2*)(xl + (size_t)s4.y * D + lane2);
            float2 l2 = *(const float2*)(xl + (size_t)s4.z * D + lane2);
            float2 l3 = *(const float2*)(xl + (size_t)s4.w * D + lane2);
            acc.x = fmaf(w4.x, l0.x, acc.x); acc.y = fmaf(w4.x, l0.y, acc.y);
            acc.x = fmaf(w4.y, l1.x, acc.x); acc.y = fmaf(w4.y, l1.y, acc.y);
            acc.x = fmaf(w4.z, l2.x, acc.x); acc.y = fmaf(w4.z, l2.y, acc.y);
            acc.x = fmaf(w4.w, l3.x, acc.x); acc.y = fmaf(w4.w, l3.y, acc.y);
        }
    }
    // single wave-reduce of z per destination
#pragma unroll
    for (int off = 32; off; off >>= 1) z += __shfl_xor(z, off);
    float inv = 1.f / z;
    float2 bv = *(const float2*)(bias + lane2);
    float2 o = { leaky(acc.x * inv + bv.x), leaky(acc.y * inv + bv.y) };
    *(float2*)(f + (size_t)t * D + lane2) = o;
}

// ---------------- K5: MLP layer 1 (round-2 exact) ----------------
__global__ __launch_bounds__(256) void k_mlp1(const float* __restrict__ f,
                                              const float* __restrict__ W1,
                                              float* __restrict__ partials) {
    const int rpb = GD / MB;              // 625 rows per block
    int r0 = blockIdx.x * rpb;
    int wave = threadIdx.x >> 6, lane = threadIdx.x & 63;
    float2 acc = { 0.f, 0.f };
#pragma unroll 4
    for (int n = r0 + wave; n < r0 + rpb; n += 4) {
        float fv = f[n];
        float2 w2 = *(const float2*)(W1 + (size_t)n * D + lane * 2);
        acc.x = fmaf(fv, w2.x, acc.x);
        acc.y = fmaf(fv, w2.y, acc.y);
    }
    __shared__ float2 red[4][64];
    red[wave][lane] = acc;
    __syncthreads();
    if (wave == 0) {
        float2 s = red[0][lane];
        s.x += red[1][lane].x + red[2][lane].x + red[3][lane].x;
        s.y += red[1][lane].y + red[2][lane].y + red[3][lane].y;
        *(float2*)(partials + blockIdx.x * D + lane * 2) = s;
    }
}

// ---------------- K6: 8-block column-sliced reduce + relu + dot W2 (round-10 exact) ----------------
__global__ __launch_bounds__(1024) void k_final8(const float* __restrict__ partials,
                                                 const float* __restrict__ b1,
                                                 const float* __restrict__ W2,
                                                 const float* __restrict__ b2,
                                                 float* __restrict__ out) {
    int tid = threadIdx.x;
    int rg = tid >> 4;
    int cl = tid & 15;
    int c = blockIdx.x * 16 + cl;
    float s = 0.f;
    for (int r = rg; r < MB; r += 64) s += partials[r * D + c];
    __shared__ float red[64][16];
    red[rg][cl] = s;
    __syncthreads();
    if (tid < 128) {
        int cc = tid & 15, seg = tid >> 4;
        float t2 = red[seg * 8][cc];
        for (int m = 1; m < 8; ++m) t2 += red[seg * 8 + m][cc];
        red[seg * 8][cc] = t2;
    }
    __syncthreads();
    if (tid < 16) {
        float tot = 0.f;
        for (int m = 0; m < 8; ++m) tot += red[m * 8][tid];
        float h1 = fmaxf(tot + b1[blockIdx.x * 16 + tid], 0.f);
        red[0][tid] = h1 * W2[blockIdx.x * 16 + tid];
    }
    __syncthreads();
    if (tid == 0) {
        float o = 0.f;
        for (int m = 0; m < 16; ++m) o += red[0][m];
        if (blockIdx.x == 0) o += b2[0];
        atomicAdd(out, o);
    }
}

extern "C" void kernel_launch(void* const* d_in, const int* in_sizes, int n_in,
                              void* d_out, int out_size, void* d_ws, size_t ws_size,
                              hipStream_t stream) {
    const float* x    = (const float*)d_in[0];
    const int*   ei   = (const int*)d_in[1];
    const float* Win  = (const float*)d_in[2];
    const float* bin  = (const float*)d_in[3];
    const float* Wl   = (const float*)d_in[4];
    const float* bl   = (const float*)d_in[5];
    const float* Wr   = (const float*)d_in[6];
    const float* br   = (const float*)d_in[7];
    const float* att  = (const float*)d_in[8];
    const float* bias = (const float*)d_in[9];
    const float* W1   = (const float*)d_in[10];
    const float* b1   = (const float*)d_in[11];
    const float* W2   = (const float*)d_in[12];
    const float* b2   = (const float*)d_in[13];
    float* out = (float*)d_out;

    float* ws       = (float*)d_ws;
    float* h        = ws;                 // GD
    float* xl       = h  + GD;            // GD
    float* xr       = xl + GD;            // GD
    float* f        = xr + GD;            // GD
    float* partials = f  + GD;            // MB*D
    int*   ssrc     = (int*)(partials + (size_t)MB * D);  // EG
    int*   cnt      = ssrc + EG;          // G
    int*   rowptr   = cnt + G;            // G+1
    int*   cursor   = rowptr + G + 1;     // G

    const int* srcA = ei;
    const int* dstA = ei + E;

    hipMemsetAsync(cnt, 0, G * sizeof(int), stream);
    k_fuseA<<<NB_PG + NB_H, 256, 0, stream>>>(x, Win, bin, h, dstA, cnt, out);
    k_scan<<<1, 256, 0, stream>>>(cnt, rowptr, cursor);
    k_fuse2<<<NBX + NB_H, 256, 0, stream>>>(h, Wl, bl, Wr, br, xl, xr, srcA, dstA, cursor, ssrc);
    k_agg<<<(G + 3) / 4, 256, 0, stream>>>(rowptr, ssrc, xl, xr, att, bias, f);
    k_mlp1<<<MB, 256, 0, stream>>>(f, W1, partials);
    k_final8<<<8, 1024, 0, stream>>>(partials, b1, W2, b2, out);
}

// Round 13
// 173.618 us; speedup vs baseline: 7.3999x; 1.0266x over previous
//
#include <hip/hip_runtime.h>
#include <math.h>

#define G 5000
#define IN 64
#define D 128
#define E 240000
#define EG (E + G)
#define SLOPE 0.2f
#define GD (G * D)
#define NB_M 1250        // aggmlp blocks (4 dests each)
#define GPB2 10
#define NBX (G / GPB2)   // 500 xlxr tiles
#define NB_PG 1250       // pergene blocks
#define NB_H 240         // hist/bucket blocks (61440 int4 units >= 61250)

__device__ __forceinline__ float leaky(float v) { return v >= 0.f ? v : SLOPE * v; }

// ---------------- K_A: pergene (blocks 0..1249) + hist (blocks 1250..1489) + zero out ----------------
__global__ __launch_bounds__(256) void k_fuseA(const float* __restrict__ x,
                                               const float* __restrict__ Win,
                                               const float* __restrict__ bin,
                                               float* __restrict__ h,
                                               const int* __restrict__ dstA,
                                               int* __restrict__ cnt,
                                               float* __restrict__ outz) {
    if (blockIdx.x == 0 && threadIdx.x == 0) *outz = 0.f;   // consumed only by k_final8 (stream-ordered)
    if (blockIdx.x < NB_PG) {
        int g = (blockIdx.x * 256 + threadIdx.x) >> 6;
        int lane = threadIdx.x & 63;
        if (g >= G) return;
        float xv = x[g * IN + lane];
        const float* W = Win + (size_t)g * IN * D + lane * 2;
        float2 acc = *(const float2*)(bin + g * D + lane * 2);
#pragma unroll
        for (int i = 0; i < IN; ++i) {
            float xi = __shfl(xv, i);
            float2 w2 = *(const float2*)(W + (size_t)i * D);
            acc.x = fmaf(xi, w2.x, acc.x);
            acc.y = fmaf(xi, w2.y, acc.y);
        }
        float2 o = { fmaxf(acc.x, 0.f), fmaxf(acc.y, 0.f) };
        *(float2*)(h + g * D + lane * 2) = o;
    } else {
        int unit = (blockIdx.x - NB_PG) * 256 + threadIdx.x;
        int base = unit * 4;
        if (base >= EG) return;
        if (base + 4 <= E) {
            int4 d4 = *(const int4*)(dstA + base);
            atomicAdd(&cnt[d4.x], 1);
            atomicAdd(&cnt[d4.y], 1);
            atomicAdd(&cnt[d4.z], 1);
            atomicAdd(&cnt[d4.w], 1);
        } else {
            for (int kk = 0; kk < 4; ++kk) {
                int i = base + kk;
                if (i < EG) {
                    int t = (i < E) ? dstA[i] : i - E;
                    atomicAdd(&cnt[t], 1);
                }
            }
        }
    }
}

// ---------------- K_scan: exclusive scan (single block) ----------------
__global__ __launch_bounds__(256) void k_scan(const int* __restrict__ cnt,
                                              int* __restrict__ rowptr,
                                              int* __restrict__ cursor) {
    __shared__ int ssum[256];
    int tid = threadIdx.x;
    const int CH = (G + 255) / 256;   // 20
    int base = tid * CH;
    int s = 0;
    for (int k = 0; k < CH; ++k) { int idx = base + k; if (idx < G) s += cnt[idx]; }
    ssum[tid] = s;
    __syncthreads();
    for (int off = 1; off < 256; off <<= 1) {
        int v = ssum[tid];
        int add = (tid >= off) ? ssum[tid - off] : 0;
        __syncthreads();
        ssum[tid] = v + add;
        __syncthreads();
    }
    int run = (tid == 0) ? 0 : ssum[tid - 1];
    for (int k = 0; k < CH; ++k) {
        int idx = base + k;
        if (idx < G) { rowptr[idx] = run; cursor[idx] = run; run += cnt[idx]; }
    }
    if (tid == 255) rowptr[G] = run;   // == EG
}

// ---------------- K_fuse2: xlxr (blocks 0..NBX-1) + bucket (blocks NBX..) (round-12 exact) ----------------
__global__ __launch_bounds__(256) void k_fuse2(const float* __restrict__ h,
                                               const float* __restrict__ Wl,
                                               const float* __restrict__ bl,
                                               const float* __restrict__ Wr,
                                               const float* __restrict__ br,
                                               float* __restrict__ xl,
                                               float* __restrict__ xr,
                                               const int* __restrict__ srcA,
                                               const int* __restrict__ dstA,
                                               int* __restrict__ cursor,
                                               int* __restrict__ ssrc) {
    if (blockIdx.x < NBX) {
        int g0 = blockIdx.x * GPB2;
        int wv = __builtin_amdgcn_readfirstlane(threadIdx.x >> 6);
        int half = wv >> 1;
        int sub  = wv & 1;
        int lane = threadIdx.x & 63;
        int d = lane * 2;
        const float* W = half ? Wr : Wl;
        const float* bb = half ? br : bl;
        float* o = half ? xr : xl;
        float2 bv = *(const float2*)(bb + d);
        float2 acc0 = bv, acc1 = bv, acc2 = bv, acc3 = bv, acc4 = bv;
        const float* hr = h + (size_t)(g0 + sub * 5) * D;
        for (int k4 = 0; k4 < 32; ++k4) {
            int k = k4 * 4;
            float2 w0 = *(const float2*)(W + (k + 0) * D + d);
            float2 w1 = *(const float2*)(W + (k + 1) * D + d);
            float2 w2 = *(const float2*)(W + (k + 2) * D + d);
            float2 w3 = *(const float2*)(W + (k + 3) * D + d);
            float4 h0 = *(const float4*)(hr + 0 * D + k);
            float4 h1 = *(const float4*)(hr + 1 * D + k);
            float4 h2 = *(const float4*)(hr + 2 * D + k);
            float4 h3 = *(const float4*)(hr + 3 * D + k);
            float4 h4 = *(const float4*)(hr + 4 * D + k);
            acc0.x = fmaf(h0.x, w0.x, acc0.x); acc0.y = fmaf(h0.x, w0.y, acc0.y);
            acc0.x = fmaf(h0.y, w1.x, acc0.x); acc0.y = fmaf(h0.y, w1.y, acc0.y);
            acc0.x = fmaf(h0.z, w2.x, acc0.x); acc0.y = fmaf(h0.z, w2.y, acc0.y);
            acc0.x = fmaf(h0.w, w3.x, acc0.x); acc0.y = fmaf(h0.w, w3.y, acc0.y);
            acc1.x = fmaf(h1.x, w0.x, acc1.x); acc1.y = fmaf(h1.x, w0.y, acc1.y);
            acc1.x = fmaf(h1.y, w1.x, acc1.x); acc1.y = fmaf(h1.y, w1.y, acc1.y);
            acc1.x = fmaf(h1.z, w2.x, acc1.x); acc1.y = fmaf(h1.z, w2.y, acc1.y);
            acc1.x = fmaf(h1.w, w3.x, acc1.x); acc1.y = fmaf(h1.w, w3.y, acc1.y);
            acc2.x = fmaf(h2.x, w0.x, acc2.x); acc2.y = fmaf(h2.x, w0.y, acc2.y);
            acc2.x = fmaf(h2.y, w1.x, acc2.x); acc2.y = fmaf(h2.y, w1.y, acc2.y);
            acc2.x = fmaf(h2.z, w2.x, acc2.x); acc2.y = fmaf(h2.z, w2.y, acc2.y);
            acc2.x = fmaf(h2.w, w3.x, acc2.x); acc2.y = fmaf(h2.w, w3.y, acc2.y);
            acc3.x = fmaf(h3.x, w0.x, acc3.x); acc3.y = fmaf(h3.x, w0.y, acc3.y);
            acc3.x = fmaf(h3.y, w1.x, acc3.x); acc3.y = fmaf(h3.y, w1.y, acc3.y);
            acc3.x = fmaf(h3.z, w2.x, acc3.x); acc3.y = fmaf(h3.z, w2.y, acc3.y);
            acc3.x = fmaf(h3.w, w3.x, acc3.x); acc3.y = fmaf(h3.w, w3.y, acc3.y);
            acc4.x = fmaf(h4.x, w0.x, acc4.x); acc4.y = fmaf(h4.x, w0.y, acc4.y);
            acc4.x = fmaf(h4.y, w1.x, acc4.x); acc4.y = fmaf(h4.y, w1.y, acc4.y);
            acc4.x = fmaf(h4.z, w2.x, acc4.x); acc4.y = fmaf(h4.z, w2.y, acc4.y);
            acc4.x = fmaf(h4.w, w3.x, acc4.x); acc4.y = fmaf(h4.w, w3.y, acc4.y);
        }
        int gbase = g0 + sub * 5;
        *(float2*)(o + (size_t)(gbase + 0) * D + d) = acc0;
        *(float2*)(o + (size_t)(gbase + 1) * D + d) = acc1;
        *(float2*)(o + (size_t)(gbase + 2) * D + d) = acc2;
        *(float2*)(o + (size_t)(gbase + 3) * D + d) = acc3;
        *(float2*)(o + (size_t)(gbase + 4) * D + d) = acc4;
    } else {
        int base = ((blockIdx.x - NBX) * 256 + threadIdx.x) * 4;
        if (base >= EG) return;
        if (base + 4 <= E) {
            int4 s4 = *(const int4*)(srcA + base);
            int4 d4 = *(const int4*)(dstA + base);
            int p;
            p = atomicAdd(&cursor[d4.x], 1); ssrc[p] = s4.x;
            p = atomicAdd(&cursor[d4.y], 1); ssrc[p] = s4.y;
            p = atomicAdd(&cursor[d4.z], 1); ssrc[p] = s4.z;
            p = atomicAdd(&cursor[d4.w], 1); ssrc[p] = s4.w;
        } else {
            for (int kk = 0; kk < 4; ++kk) {
                int i = base + kk;
                if (i < EG) {
                    int s, t;
                    if (i < E) { s = srcA[i]; t = dstA[i]; }
                    else { s = i - E; t = s; }
                    int p = atomicAdd(&cursor[t], 1);
                    ssrc[p] = s;
                }
            }
        }
    }
}

// ---------------- K_AGGMLP: agg (round-12 body) fused with W1 GEMV slab ----------------
// 1250 blocks x 4 waves; wave w owns dest t = bid*4+w. Agg result stays in regs,
// then the wave streams W1 rows [t*128, t*128+128) (contiguous 64KB) and
// accumulates 128-col partials. No f buffer.
__global__ __launch_bounds__(256) void k_aggmlp(const int* __restrict__ rowptr,
                                                const int* __restrict__ ssrc,
                                                const float* __restrict__ xl,
                                                const float* __restrict__ xr,
                                                const float* __restrict__ att,
                                                const float* __restrict__ bias,
                                                const float* __restrict__ W1,
                                                float* __restrict__ partials) {
    int wid = threadIdx.x >> 6;
    int lane = threadIdx.x & 63;
    int t = __builtin_amdgcn_readfirstlane(blockIdx.x * 4 + wid);   // wave-uniform
    __shared__ float w_lds[4][64];
    __shared__ int   s_lds[4][64];
    __shared__ float2 red[4][64];
    const float* xrt = xr + (size_t)t * D;
    int lane2 = lane * 2;
    float2 acc = { 0.f, 0.f };
    float z = 0.f;
    int e0 = rowptr[t], e1 = rowptr[t + 1];
    for (int base = e0; base < e1; base += 64) {
        int nv = e1 - base; if (nv > 64) nv = 64;
        int mye = base + lane;
        int s = ssrc[mye < e1 ? mye : e1 - 1];
        // phase 1: per-lane full-D logit
        const float* xls = xl + (size_t)s * D;
        float v0 = 0.f, v1 = 0.f;
#pragma unroll
        for (int dc = 0; dc < D; dc += 8) {
            float4 xa = *(const float4*)(xls + dc);
            float4 xb = *(const float4*)(xls + dc + 4);
            float4 ra = *(const float4*)(xrt + dc);
            float4 rb = *(const float4*)(xrt + dc + 4);
            float4 aa = *(const float4*)(att + dc);
            float4 ab = *(const float4*)(att + dc + 4);
            v0 = fmaf(aa.x, leaky(xa.x + ra.x), v0);
            v0 = fmaf(aa.y, leaky(xa.y + ra.y), v0);
            v0 = fmaf(aa.z, leaky(xa.z + ra.z), v0);
            v0 = fmaf(aa.w, leaky(xa.w + ra.w), v0);
            v1 = fmaf(ab.x, leaky(xb.x + rb.x), v1);
            v1 = fmaf(ab.y, leaky(xb.y + rb.y), v1);
            v1 = fmaf(ab.z, leaky(xb.z + rb.z), v1);
            v1 = fmaf(ab.w, leaky(xb.w + rb.w), v1);
        }
        float w = (lane < nv) ? expf(v0 + v1) : 0.f;
        z += w;
        w_lds[wid][lane] = w;     // same-wave write->read: lockstep
        s_lds[wid][lane] = s;
        // phase 2: column-major weighted aggregate
        for (int e = 0; e < nv; e += 4) {
            float4 w4 = *(const float4*)&w_lds[wid][e];
            int4   s4 = *(const int4*)&s_lds[wid][e];
            float2 l0 = *(const float2*)(xl + (size_t)s4.x * D + lane2);
            float2 l1 = *(const float2*)(xl + (size_t)s4.y * D + lane2);
            float2 l2 = *(const float2*)(xl + (size_t)s4.z * D + lane2);
            float2 l3 = *(const float2*)(xl + (size_t)s4.w * D + lane2);
            acc.x = fmaf(w4.x, l0.x, acc.x); acc.y = fmaf(w4.x, l0.y, acc.y);
            acc.x = fmaf(w4.y, l1.x, acc.x); acc.y = fmaf(w4.y, l1.y, acc.y);
            acc.x = fmaf(w4.z, l2.x, acc.x); acc.y = fmaf(w4.z, l2.y, acc.y);
            acc.x = fmaf(w4.w, l3.x, acc.x); acc.y = fmaf(w4.w, l3.y, acc.y);
        }
    }
#pragma unroll
    for (int off = 32; off; off >>= 1) z += __shfl_xor(z, off);
    float inv = 1.f / z;
    float2 bv = *(const float2*)(bias + lane2);
    float2 o = { leaky(acc.x * inv + bv.x), leaky(acc.y * inv + bv.y) };   // = f[t][lane2..lane2+1]

    // ---- fused MLP1 slab: rows t*128 .. t*128+127 of W1, f_t broadcast from regs ----
    const float* W1p = W1 + (size_t)t * D * D + lane2;
    float2 m = { 0.f, 0.f };
#pragma unroll 8
    for (int dp = 0; dp < 64; ++dp) {
        float fx = __shfl(o.x, dp);
        float fy = __shfl(o.y, dp);
        float2 wa = *(const float2*)(W1p + (size_t)(2 * dp) * D);
        float2 wb = *(const float2*)(W1p + (size_t)(2 * dp + 1) * D);
        m.x = fmaf(fx, wa.x, m.x); m.y = fmaf(fx, wa.y, m.y);
        m.x = fmaf(fy, wb.x, m.x); m.y = fmaf(fy, wb.y, m.y);
    }
    red[wid][lane] = m;
    __syncthreads();
    if (wid == 0) {
        float2 s0 = red[0][lane], s1 = red[1][lane], s2 = red[2][lane], s3 = red[3][lane];
        float2 s = { s0.x + s1.x + s2.x + s3.x, s0.y + s1.y + s2.y + s3.y };
        *(float2*)(partials + (size_t)blockIdx.x * D + lane2) = s;
    }
}

// ---------------- K6: 8-block column-sliced reduce + relu + dot W2 ----------------
__global__ __launch_bounds__(1024) void k_final8(const float* __restrict__ partials,
                                                 const float* __restrict__ b1,
                                                 const float* __restrict__ W2,
                                                 const float* __restrict__ b2,
                                                 float* __restrict__ out) {
    int tid = threadIdx.x;
    int rg = tid >> 4;
    int cl = tid & 15;
    int c = blockIdx.x * 16 + cl;
    float s = 0.f;
    for (int r = rg; r < NB_M; r += 64) s += partials[(size_t)r * D + c];
    __shared__ float red[64][16];
    red[rg][cl] = s;
    __syncthreads();
    if (tid < 128) {
        int cc = tid & 15, seg = tid >> 4;
        float t2 = red[seg * 8][cc];
        for (int m = 1; m < 8; ++m) t2 += red[seg * 8 + m][cc];
        red[seg * 8][cc] = t2;
    }
    __syncthreads();
    if (tid < 16) {
        float tot = 0.f;
        for (int m = 0; m < 8; ++m) tot += red[m * 8][tid];
        float h1 = fmaxf(tot + b1[blockIdx.x * 16 + tid], 0.f);
        red[0][tid] = h1 * W2[blockIdx.x * 16 + tid];
    }
    __syncthreads();
    if (tid == 0) {
        float o = 0.f;
        for (int m = 0; m < 16; ++m) o += red[0][m];
        if (blockIdx.x == 0) o += b2[0];
        atomicAdd(out, o);
    }
}

extern "C" void kernel_launch(void* const* d_in, const int* in_sizes, int n_in,
                              void* d_out, int out_size, void* d_ws, size_t ws_size,
                              hipStream_t stream) {
    const float* x    = (const float*)d_in[0];
    const int*   ei   = (const int*)d_in[1];
    const float* Win  = (const float*)d_in[2];
    const float* bin  = (const float*)d_in[3];
    const float* Wl   = (const float*)d_in[4];
    const float* bl   = (const float*)d_in[5];
    const float* Wr   = (const float*)d_in[6];
    const float* br   = (const float*)d_in[7];
    const float* att  = (const float*)d_in[8];
    const float* bias = (const float*)d_in[9];
    const float* W1   = (const float*)d_in[10];
    const float* b1   = (const float*)d_in[11];
    const float* W2   = (const float*)d_in[12];
    const float* b2   = (const float*)d_in[13];
    float* out = (float*)d_out;

    float* ws       = (float*)d_ws;
    float* h        = ws;                 // GD
    float* xl       = h  + GD;            // GD
    float* xr       = xl + GD;            // GD
    float* partials = xr + GD;            // NB_M*D
    int*   ssrc     = (int*)(partials + (size_t)NB_M * D);  // EG
    int*   cnt      = ssrc + EG;          // G
    int*   rowptr   = cnt + G;            // G+1
    int*   cursor   = rowptr + G + 1;     // G

    const int* srcA = ei;
    const int* dstA = ei + E;

    hipMemsetAsync(cnt, 0, G * sizeof(int), stream);
    k_fuseA<<<NB_PG + NB_H, 256, 0, stream>>>(x, Win, bin, h, dstA, cnt, out);
    k_scan<<<1, 256, 0, stream>>>(cnt, rowptr, cursor);
    k_fuse2<<<NBX + NB_H, 256, 0, stream>>>(h, Wl, bl, Wr, br, xl, xr, srcA, dstA, cursor, ssrc);
    k_aggmlp<<<NB_M, 256, 0, stream>>>(rowptr, ssrc, xl, xr, att, bias, W1, partials);
    k_final8<<<8, 1024, 0, stream>>>(partials, b1, W2, b2, out);
}